// Round 1
// baseline (45.526 us; speedup 1.0000x reference)
//
#include <hip/hip_runtime.h>
#include <hip/hip_bf16.h>

#define N_NODES 4096
#define IN_FEAT 128
#define OUT_FEAT 64
#define NHEAD 4
#define HID 256           // NHEAD * OUT_FEAT
#define NEG_SLOPE 0.2f
#define MAXD 1024         // neighbor-list capacity (expected max degree ~75)

// ---------------------------------------------------------------------------
// Kernel 1: h = x @ W  (4096x128 @ 128x256), fused attn_src/attn_tgt reductions.
// 256 blocks x 256 threads; block handles 16 rows. x tile transposed in LDS.
// ---------------------------------------------------------------------------
__global__ __launch_bounds__(256) void k_h_attn(
    const float* __restrict__ x, const float* __restrict__ W,
    const float* __restrict__ a, __hip_bfloat16* __restrict__ h_bf,
    float* __restrict__ attn_src, float* __restrict__ attn_tgt)
{
    __shared__ float xs[IN_FEAT][16];   // xs[k][r]
    const int t = threadIdx.x;
    const int row0 = blockIdx.x * 16;

    // Stage x rows (16 x 128 f32 = 8KB), transposed. Coalesced float4 loads.
    const float4* xsrc = reinterpret_cast<const float4*>(x + (size_t)row0 * IN_FEAT);
    #pragma unroll
    for (int u = 0; u < 2; ++u) {
        float4 v = xsrc[t * 2 + u];
        int li = t * 8 + u * 4;        // flat element index in 16x128 tile
        int r = li >> 7;
        int k = li & 127;
        xs[k + 0][r] = v.x; xs[k + 1][r] = v.y;
        xs[k + 2][r] = v.z; xs[k + 3][r] = v.w;
    }
    __syncthreads();

    float acc[16];
    #pragma unroll
    for (int r = 0; r < 16; ++r) acc[r] = 0.f;

    const int c = t;  // output column 0..255
    #pragma unroll 4
    for (int k = 0; k < IN_FEAT; ++k) {
        float w = W[k * HID + c];                    // coalesced, L2-resident
        const float4* xr = reinterpret_cast<const float4*>(&xs[k][0]);  // broadcast
        float4 x0 = xr[0], x1 = xr[1], x2 = xr[2], x3 = xr[3];
        acc[0]  += x0.x * w; acc[1]  += x0.y * w; acc[2]  += x0.z * w; acc[3]  += x0.w * w;
        acc[4]  += x1.x * w; acc[5]  += x1.y * w; acc[6]  += x1.z * w; acc[7]  += x1.w * w;
        acc[8]  += x2.x * w; acc[9]  += x2.y * w; acc[10] += x2.z * w; acc[11] += x2.w * w;
        acc[12] += x3.x * w; acc[13] += x3.y * w; acc[14] += x3.z * w; acc[15] += x3.w * w;
    }

    // Fused attn reductions: wave w == head w (c = head*64 + f, f = lane).
    const int lane = t & 63;
    const int head = t >> 6;
    const float asrc = a[head * (2 * OUT_FEAT) + lane];
    const float atgt = a[head * (2 * OUT_FEAT) + OUT_FEAT + lane];
    #pragma unroll
    for (int r = 0; r < 16; ++r) {
        float s = acc[r] * asrc;
        float g = acc[r] * atgt;
        #pragma unroll
        for (int d = 32; d; d >>= 1) {
            s += __shfl_xor(s, d, 64);
            g += __shfl_xor(g, d, 64);
        }
        if (lane == 0) {
            attn_src[(size_t)(row0 + r) * NHEAD + head] = s;
            attn_tgt[(size_t)(row0 + r) * NHEAD + head] = g;
        }
        h_bf[(size_t)(row0 + r) * HID + c] = __float2bfloat16(acc[r]);
    }
}

// ---------------------------------------------------------------------------
// Kernel 2: per node i — compact neighbor list from adj row (+ self loop),
// per-head masked softmax of LeakyReLU(src_i + tgt_j), aggregate h rows.
// 4096 blocks x 256 threads (wave w handles head w).
// ---------------------------------------------------------------------------
__global__ __launch_bounds__(256) void k_gat(
    const float* __restrict__ adj, const __hip_bfloat16* __restrict__ h_bf,
    const float* __restrict__ attn_src, const float* __restrict__ attn_tgt,
    float* __restrict__ out)
{
    __shared__ unsigned short nbr[MAXD];
    __shared__ float p[NHEAD][MAXD];
    __shared__ int wsum[4];

    const int i = blockIdx.x;
    const int t = threadIdx.x;
    const int lane = t & 63;
    const int wv = t >> 6;

    // ---- Stage A: scan adj row, build neighbor list (deterministic order) ----
    // Perfectly coalesced: instruction u reads elements [u*1024 + t*4 .. +3].
    const float4* arow = reinterpret_cast<const float4*>(adj + (size_t)i * N_NODES);
    unsigned mask16 = 0;
    #pragma unroll
    for (int u = 0; u < 4; ++u) {
        float4 v = arow[u * 256 + t];
        int jb = u * 1024 + t * 4;
        if (v.x != 0.f || (jb + 0) == i) mask16 |= 1u << (u * 4 + 0);
        if (v.y != 0.f || (jb + 1) == i) mask16 |= 1u << (u * 4 + 1);
        if (v.z != 0.f || (jb + 2) == i) mask16 |= 1u << (u * 4 + 2);
        if (v.w != 0.f || (jb + 3) == i) mask16 |= 1u << (u * 4 + 3);
    }
    int cnt = __popc(mask16);

    // exclusive prefix over 256 threads: wave-scan + cross-wave offsets
    int incl = cnt;
    #pragma unroll
    for (int d = 1; d < 64; d <<= 1) {
        int u2 = __shfl_up(incl, d, 64);
        if (lane >= d) incl += u2;
    }
    if (lane == 63) wsum[wv] = incl;
    __syncthreads();
    int base = 0;
    #pragma unroll
    for (int w = 0; w < 4; ++w) base += (w < wv) ? wsum[w] : 0;
    int total = wsum[0] + wsum[1] + wsum[2] + wsum[3];
    if (total > MAXD) total = MAXD;   // cannot happen for 1% density; safety
    int off = base + incl - cnt;

    unsigned m = mask16;
    while (m) {
        int b = __ffs((int)m) - 1;
        m &= m - 1;
        int j = ((b >> 2) * 1024) + t * 4 + (b & 3);
        if (off < MAXD) nbr[off] = (unsigned short)j;
        ++off;
    }
    __syncthreads();

    // ---- Stage B: per-head softmax (wave wv owns head wv) ----
    const int head = wv;
    const float srcv = attn_src[(size_t)i * NHEAD + head];
    float e_max = -1e30f;
    for (int idx = lane; idx < total; idx += 64) {
        int j = nbr[idx];
        float e = srcv + attn_tgt[(size_t)j * NHEAD + head];
        e = (e > 0.f) ? e : NEG_SLOPE * e;
        p[head][idx] = e;
        e_max = fmaxf(e_max, e);
    }
    #pragma unroll
    for (int d = 32; d; d >>= 1) e_max = fmaxf(e_max, __shfl_xor(e_max, d, 64));
    float ssum = 0.f;
    for (int idx = lane; idx < total; idx += 64) {
        float pe = __expf(p[head][idx] - e_max);
        p[head][idx] = pe;
        ssum += pe;
    }
    #pragma unroll
    for (int d = 32; d; d >>= 1) ssum += __shfl_xor(ssum, d, 64);
    const float inv = 1.0f / ssum;   // >=1 neighbor always (self loop)

    // ---- Stage C: aggregate out[i, head, f] = sum_j p_j * h[j, head, f] * inv
    // (wave-local: p[head][*] produced and consumed by the same wave)
    const int f = lane;
    const __hip_bfloat16* hcol = h_bf + head * OUT_FEAT + f;
    float acc = 0.f;
    for (int idx = 0; idx < total; ++idx) {
        int j = nbr[idx];                                  // LDS broadcast
        acc += p[head][idx] * __bfloat162float(hcol[(size_t)j * HID]);
    }
    out[(size_t)i * HID + t] = acc * inv;
}

// ---------------------------------------------------------------------------
extern "C" void kernel_launch(void* const* d_in, const int* in_sizes, int n_in,
                              void* d_out, int out_size, void* d_ws, size_t ws_size,
                              hipStream_t stream)
{
    const float* x   = (const float*)d_in[0];   // (4096,128)
    const float* adj = (const float*)d_in[1];   // (4096,4096)
    const float* W   = (const float*)d_in[2];   // (128,256)
    const float* a   = (const float*)d_in[3];   // (4,128)
    float* out = (float*)d_out;                 // (4096,256)

    char* ws = (char*)d_ws;
    __hip_bfloat16* h_bf = (__hip_bfloat16*)ws;                       // 2 MB
    float* attn_src = (float*)(ws + (size_t)N_NODES * HID * 2);      // 64 KB
    float* attn_tgt = attn_src + (size_t)N_NODES * NHEAD;            // 64 KB

    k_h_attn<<<N_NODES / 16, 256, 0, stream>>>(x, W, a, h_bf, attn_src, attn_tgt);
    k_gat<<<N_NODES, 256, 0, stream>>>(adj, h_bf, attn_src, attn_tgt, out);
}